// Round 1
// baseline (136.703 us; speedup 1.0000x reference)
//
#include <hip/hip_runtime.h>

#define BB 4
#define NN 2048
#define FF 512
#define ALPHA 0.2f

typedef unsigned short u16;
typedef unsigned int u32;
typedef __attribute__((ext_vector_type(8))) short bf16x8;
typedef __attribute__((ext_vector_type(4))) float f32x4;

__device__ __forceinline__ u16 f2bf(float x) {
  union { float f; u32 u; } v; v.f = x;
  u32 r = v.u + 0x7fffu + ((v.u >> 16) & 1u);
  return (u16)(r >> 16);
}
__device__ __forceinline__ float bf2f(u16 u) {
  union { u32 i; float f; } v; v.i = ((u32)u) << 16; return v.f;
}
__device__ __forceinline__ float leaky(float x) { return x >= 0.f ? x : ALPHA * x; }

// -------------------------------------------------------------------------
// K1: Wh = h @ W  (bf16 MFMA), output TRANSPOSED per batch: whT[b][f][i]
// grid (64 m-tiles, 4 n-tiles), 256 threads (4 waves, 2x2, each 64x64)
// -------------------------------------------------------------------------
__global__ __launch_bounds__(256) void k_wh(const float* __restrict__ h,
                                            const float* __restrict__ W,
                                            u16* __restrict__ whT) {
  __shared__ __attribute__((aligned(16))) u16 As[128][40];  // [i][k] pad->80B rows
  __shared__ __attribute__((aligned(16))) u16 Bs[128][40];  // [f][k]
  const int m0 = blockIdx.x * 128;          // global row = b*NN + i
  const int f0 = blockIdx.y * 128;
  const int tid = threadIdx.x;
  const int wave = tid >> 6, lane = tid & 63;
  const int wm = (wave >> 1) * 64, wn = (wave & 1) * 64;

  f32x4 acc[4][4];
#pragma unroll
  for (int i = 0; i < 4; i++)
#pragma unroll
    for (int j = 0; j < 4; j++) acc[i][j] = f32x4{0.f, 0.f, 0.f, 0.f};

  for (int k0 = 0; k0 < FF; k0 += 32) {
    // stage A: h[m0..+128][k0..+32] -> As[i][k] (fp32 -> bf16)
    {
      const int kc = tid & 7, ib = tid >> 3;
#pragma unroll
      for (int p = 0; p < 4; p++) {
        const int i = ib + p * 32;
        float4 v = *(const float4*)(h + (size_t)(m0 + i) * FF + k0 + kc * 4);
        ushort4 o;
        o.x = f2bf(v.x); o.y = f2bf(v.y); o.z = f2bf(v.z); o.w = f2bf(v.w);
        *(ushort4*)(&As[i][kc * 4]) = o;
      }
    }
    // stage B: W[k0..+32][f0..+128] -> Bs[f][k] (transposed)
    {
      const int fc = tid & 31, kb = tid >> 5;
#pragma unroll
      for (int p = 0; p < 4; p++) {
        const int k = kb + p * 8;
        float4 v = *(const float4*)(W + (size_t)(k0 + k) * FF + f0 + fc * 4);
        Bs[fc * 4 + 0][k] = f2bf(v.x);
        Bs[fc * 4 + 1][k] = f2bf(v.y);
        Bs[fc * 4 + 2][k] = f2bf(v.z);
        Bs[fc * 4 + 3][k] = f2bf(v.w);
      }
    }
    __syncthreads();
    const int r = lane & 15, kq = lane >> 4;
    bf16x8 af[4], bfv[4];
#pragma unroll
    for (int mi = 0; mi < 4; mi++)
      af[mi] = *(const bf16x8*)(&As[wm + mi * 16 + r][kq * 8]);
#pragma unroll
    for (int ni = 0; ni < 4; ni++)
      bfv[ni] = *(const bf16x8*)(&Bs[wn + ni * 16 + r][kq * 8]);
#pragma unroll
    for (int mi = 0; mi < 4; mi++)
#pragma unroll
      for (int ni = 0; ni < 4; ni++)
        acc[mi][ni] = __builtin_amdgcn_mfma_f32_16x16x32_bf16(af[mi], bfv[ni], acc[mi][ni], 0, 0, 0);
    __syncthreads();
  }
  // epilogue: C/D layout col=lane&15 (f), row=(lane>>4)*4+r (i). Write whT[b][f][i] bf16.
  const int b = m0 >> 11;
  const int ibase = (m0 & (NN - 1));
  const int r = lane & 15, rg = lane >> 4;
#pragma unroll
  for (int mi = 0; mi < 4; mi++)
#pragma unroll
    for (int ni = 0; ni < 4; ni++) {
      const int f = f0 + wn + ni * 16 + r;
      const int i = ibase + wm + mi * 16 + rg * 4;
      ushort4 o;
      o.x = f2bf(acc[mi][ni][0]);
      o.y = f2bf(acc[mi][ni][1]);
      o.z = f2bf(acc[mi][ni][2]);
      o.w = f2bf(acc[mi][ni][3]);
      *(ushort4*)(whT + ((size_t)b * FF + f) * NN + i) = o;
    }
}

// -------------------------------------------------------------------------
// K2: s1[b][i] = sum_f whT[b][f][i]*a[f]; s2 same with a[FF+f]
// grid (8 i-chunks, 4 f-chunks, 4 b), 256 threads. atomicAdd partials.
// -------------------------------------------------------------------------
__global__ __launch_bounds__(256) void k_s(const u16* __restrict__ whT,
                                           const float* __restrict__ a,
                                           float* __restrict__ s1,
                                           float* __restrict__ s2) {
  const int b = blockIdx.z;
  const int i = blockIdx.x * 256 + threadIdx.x;
  const int f0 = blockIdx.y * 128;
  float a1 = 0.f, a2 = 0.f;
  for (int f = f0; f < f0 + 128; f++) {
    float v = bf2f(whT[((size_t)b * FF + f) * NN + i]);
    a1 += v * a[f];
    a2 += v * a[FF + f];
  }
  atomicAdd(&s1[b * NN + i], a1);
  atomicAdd(&s2[b * NN + i], a2);
}

// -------------------------------------------------------------------------
// K3: l[b][j] = sum_i adj[b][i][j] * exp(leaky(s1[i]+s2[j]))
// grid (8 j-chunks, 8 i-chunks, 4 b), 256 threads, coalesced along j.
// -------------------------------------------------------------------------
__global__ __launch_bounds__(256) void k_l(const int* __restrict__ adj,
                                           const float* __restrict__ s1,
                                           const float* __restrict__ s2,
                                           float* __restrict__ l) {
  const int b = blockIdx.z;
  const int j = blockIdx.x * 256 + threadIdx.x;
  const int i0 = blockIdx.y * 256;
  const float s2j = s2[b * NN + j];
  const int* ap = adj + ((size_t)b * NN + i0) * NN + j;
  const float* s1p = s1 + b * NN + i0;
  float acc = 0.f;
#pragma unroll 4
  for (int ii = 0; ii < 256; ii++) {
    float e = s1p[ii] + s2j;
    e = e >= 0.f ? e : ALPHA * e;
    float p = __expf(e);
    acc += (ap[(size_t)ii * NN] > 0) ? p : 0.f;
  }
  atomicAdd(&l[b * NN + j], acc);
}

__global__ __launch_bounds__(256) void k_rcp(const float* __restrict__ l,
                                             float* __restrict__ rl) {
  int t = blockIdx.x * 256 + threadIdx.x;
  rl[t] = 1.0f / l[t];
}

// -------------------------------------------------------------------------
// K4: out[b][i][f] = leaky( sum_j P'[i][j] * Wh[b][j][f] )
//     P'[i][j] = adj ? exp(leaky(s1_i+s2_j)) * rl[j] : 0   (built on the fly)
// grid (64 i-tiles, 4 b), 512 threads (8 waves, each 32 rows x 64 f-cols)
// BM=32, BN=512 (full), BK=64 -> each adj element read exactly once.
// -------------------------------------------------------------------------
__global__ __launch_bounds__(512) void k_out(const int* __restrict__ adj,
                                             const float* __restrict__ s1,
                                             const float* __restrict__ s2,
                                             const float* __restrict__ rl,
                                             const u16* __restrict__ whT,
                                             float* __restrict__ out) {
  __shared__ __attribute__((aligned(16))) u16 Ps[32][72];   // [i][j] pad->144B rows
  __shared__ __attribute__((aligned(16))) u16 Bs[512][72];  // [f][j] pad->144B rows
  const int b = blockIdx.y;
  const int i0 = blockIdx.x * 32;
  const int tid = threadIdx.x;
  const int wave = tid >> 6, lane = tid & 63;
  const int wn = wave * 64;  // wave's f-range

  f32x4 acc[2][4];
#pragma unroll
  for (int i = 0; i < 2; i++)
#pragma unroll
    for (int j = 0; j < 4; j++) acc[i][j] = f32x4{0.f, 0.f, 0.f, 0.f};

  // P-gen assignment: each thread owns (pi, pj..pj+3)
  const int pj = (tid & 15) * 4;
  const int pi = tid >> 4;
  const float s1i = s1[b * NN + i0 + pi];

  for (int j0 = 0; j0 < NN; j0 += 64) {
    // stage B: whT[b][f][j0..+64] -> Bs[f][jl]  (already bf16; 16B vector copies)
    {
      const int c = tid & 7, fr = tid >> 3;
#pragma unroll
      for (int p = 0; p < 8; p++) {
        const int f = fr + p * 64;
        uint4 v = *(const uint4*)(whT + ((size_t)b * FF + f) * NN + j0 + c * 8);
        *(uint4*)(&Bs[f][c * 8]) = v;
      }
    }
    // stage P tile 32x64
    {
      int4 av = *(const int4*)(adj + ((size_t)b * NN + (i0 + pi)) * NN + j0 + pj);
      float4 s2v = *(const float4*)(s2 + b * NN + j0 + pj);
      float4 rlv = *(const float4*)(rl + b * NN + j0 + pj);
      float e0 = leaky(s1i + s2v.x), e1 = leaky(s1i + s2v.y);
      float e2 = leaky(s1i + s2v.z), e3 = leaky(s1i + s2v.w);
      float p0 = (av.x > 0) ? __expf(e0) * rlv.x : 0.f;
      float p1 = (av.y > 0) ? __expf(e1) * rlv.y : 0.f;
      float p2 = (av.z > 0) ? __expf(e2) * rlv.z : 0.f;
      float p3 = (av.w > 0) ? __expf(e3) * rlv.w : 0.f;
      ushort4 o;
      o.x = f2bf(p0); o.y = f2bf(p1); o.z = f2bf(p2); o.w = f2bf(p3);
      *(ushort4*)(&Ps[pi][pj]) = o;
    }
    __syncthreads();
    const int r = lane & 15, kq = lane >> 4;
#pragma unroll
    for (int kk = 0; kk < 2; kk++) {
      bf16x8 af[2], bfv[4];
#pragma unroll
      for (int mi = 0; mi < 2; mi++)
        af[mi] = *(const bf16x8*)(&Ps[mi * 16 + r][kk * 32 + kq * 8]);
#pragma unroll
      for (int ni = 0; ni < 4; ni++)
        bfv[ni] = *(const bf16x8*)(&Bs[wn + ni * 16 + r][kk * 32 + kq * 8]);
#pragma unroll
      for (int mi = 0; mi < 2; mi++)
#pragma unroll
        for (int ni = 0; ni < 4; ni++)
          acc[mi][ni] = __builtin_amdgcn_mfma_f32_16x16x32_bf16(af[mi], bfv[ni], acc[mi][ni], 0, 0, 0);
    }
    __syncthreads();
  }
  // epilogue: col=lane&15 (f), row=(lane>>4)*4+rr (i); apply leaky, fp32 out
  const int r = lane & 15, rg = lane >> 4;
#pragma unroll
  for (int mi = 0; mi < 2; mi++)
#pragma unroll
    for (int ni = 0; ni < 4; ni++) {
      const int f = wn + ni * 16 + r;
      const int irow = i0 + mi * 16 + rg * 4;
#pragma unroll
      for (int rr = 0; rr < 4; rr++) {
        float v = acc[mi][ni][rr];
        v = v >= 0.f ? v : ALPHA * v;
        out[((size_t)b * NN + irow + rr) * FF + f] = v;
      }
    }
}

extern "C" void kernel_launch(void* const* d_in, const int* in_sizes, int n_in,
                              void* d_out, int out_size, void* d_ws, size_t ws_size,
                              hipStream_t stream) {
  const float* h = (const float*)d_in[0];
  const float* W = (const float*)d_in[1];
  const float* a = (const float*)d_in[2];
  const int* adj = (const int*)d_in[3];
  float* out = (float*)d_out;

  char* ws = (char*)d_ws;
  u16* whT = (u16*)ws;                                // 4*512*2048*2 = 8 MiB
  float* s1 = (float*)(ws + (size_t)8388608);         // 8192 f32
  float* s2 = s1 + BB * NN;
  float* lsum = s2 + BB * NN;
  float* rl = lsum + BB * NN;

  hipMemsetAsync(s1, 0, (size_t)3 * BB * NN * sizeof(float), stream);

  k_wh<<<dim3(64, 4), 256, 0, stream>>>(h, W, whT);
  k_s<<<dim3(8, 4, 4), 256, 0, stream>>>(whT, a, s1, s2);
  k_l<<<dim3(8, 8, 4), 256, 0, stream>>>(adj, s1, s2, lsum);
  k_rcp<<<32, 256, 0, stream>>>(lsum, rl);
  k_out<<<dim3(64, 4), 512, 0, stream>>>(adj, s1, s2, rl, whT, out);
}